// Round 6
// baseline (302.707 us; speedup 1.0000x reference)
//
#include <hip/hip_runtime.h>

// Problem constants
#define IN_C   64
#define OUT_D  47          // (24-1)*2 - 2*1 + 3
#define XD     24
#define XSP    (XD*XD*XD)  // 13824
#define OSP    (OUT_D*OUT_D*OUT_D) // 103823
#define BATCH  16
#define XBYTES (BATCH*IN_C*XSP*4)  // 56,623,104 bytes

typedef float vf4 __attribute__((ext_vector_type(4)));
typedef unsigned int v4u __attribute__((ext_vector_type(4)));

// Effective weights: weff[c*64 + (pd*2+dd)*16 + (((ph*2+pw)*2+dh)*2+dw)]
// Per dim: S(p=0,d=0)={2}, S(0,1)={0,1}, S(1,0)={1,2}, S(1,1)={0}
// 64 blocks x 64 threads: thread = one weff value (sum of <=8 w-taps).
__global__ void weff_prep(const float* __restrict__ w, float* __restrict__ weff) {
    const int c = blockIdx.x;
    const int i = threadIdx.x;
    const int pd = i >> 5, dd = (i >> 4) & 1, ph = (i >> 3) & 1,
              pw = (i >> 2) & 1, dh = (i >> 1) & 1, dw = i & 1;
    const int st[2][2] = {{2, 0}, {1, 0}};   // start of S(p,d)
    const int ct[2][2] = {{1, 2}, {2, 1}};   // count of S(p,d)
    const int z0 = st[pd][dd], zc = ct[pd][dd];
    const int h0 = st[ph][dh], hc = ct[ph][dh];
    const int w0 = st[pw][dw], wn = ct[pw][dw];
    const float* wc = w + (size_t)c * 64 * 27;   // weight[c][0][*]
    float s = 0.f;
    for (int a = 0; a < zc; a++)
        for (int b = 0; b < hc; b++)
            for (int d = 0; d < wn; d++)
                s += wc[(z0 + a) * 9 + (h0 + b) * 3 + (w0 + d)];
    weff[c * 64 + i] = s;
}

// 864 blocks = 54 sp-tiles (6d x 3h x 3w, m-tile 4x8x8) x 16 n. 256 threads =
// 4 waves; wave wv owns channels [16wv,16wv+16). Lane: wq=L&1 (w-quad),
// mh=(L>>1)&7, md=L>>4. Thread computes 4 m-voxels x 8 parities = 32 accs.
// NO LDS in the channel loop: x neighborhood read straight from L1 via
// buffer loads (OOB returns 0 -> free zero-padding, no faults). LDS only
// for the final 4-group tree reduce; plain stores (no atomics).
__global__ __launch_bounds__(256, 4) void tconv(const float* __restrict__ x,
                                                const float* __restrict__ weff,
                                                const float* __restrict__ bias,
                                                float* __restrict__ out) {
    __shared__ float red[2][64 * 36];   // 18.4 KB, +1-quad pad per row
    const int b = blockIdx.x;
    const int n = b / 54;
    const int sp = b - n * 54;
    const int tz = sp / 9;
    const int r9 = sp - tz * 9;
    const int ty = r9 / 3;
    const int tx = r9 - ty * 3;
    const int Bd = tz * 4, Bh = ty * 8, Bw = tx * 8;

    const int tid = threadIdx.x;
    const int wv = tid >> 6;
    const int L  = tid & 63;
    const int wq = L & 1;
    const int mh = (L >> 1) & 7;
    const int md = L >> 4;          // 0..3
    const int mwb = Bw + 4 * wq;    // w-quad base

    __amdgpu_buffer_rsrc_t rsrc = __builtin_amdgcn_make_buffer_rsrc(
        const_cast<float*>(x), (short)0, XBYTES, 0x00020000);

    // channel-invariant row voffsets; invalid z/y rows -> 0x80000000 (OOB->0)
    unsigned rowv[9];
    #pragma unroll
    for (int zo = 0; zo < 3; zo++)
    #pragma unroll
    for (int yo = 0; yo < 3; yo++) {
        int gz = Bd + md - 1 + zo;
        int gy = Bh + mh - 1 + yo;
        bool v = ((unsigned)gz < (unsigned)XD) && ((unsigned)gy < (unsigned)XD);
        rowv[zo * 3 + yo] = v ? (unsigned)(((gz * XD + gy) * XD + mwb) * 4)
                              : 0x80000000u;
    }
    // per-lane edge deltas for the two b32 edge taps (OOB -> 0)
    const unsigned dLt = (mwb == 0)       ? 0x40000000u : (unsigned)-4;
    const unsigned dRt = (mwb + 4 >= XD)  ? 0x40000000u : 16u;

    const int ch0 = wv * 16;              // channel base (weights)
    const int sbase = (n * IN_C + ch0) * (XSP * 4);

    float acc[2][2][2][4] = {};           // [pd][ph][pw][j]

    #pragma unroll 1
    for (int cc = 0; cc < 16; cc++) {
        const int soff = sbase + cc * (XSP * 4);   // wave-uniform -> SGPR

        float xw[3][3][6];
        #pragma unroll
        for (int k = 0; k < 9; k++) {
            v4u q = __builtin_amdgcn_raw_buffer_load_b128(rsrc, (int)rowv[k], soff, 0);
            unsigned el = __builtin_amdgcn_raw_buffer_load_b32(rsrc, (int)(rowv[k] + dLt), soff, 0);
            unsigned er = __builtin_amdgcn_raw_buffer_load_b32(rsrc, (int)(rowv[k] + dRt), soff, 0);
            vf4 qf = __builtin_bit_cast(vf4, q);
            const int zo = k / 3, yo = k - 3 * (k / 3);
            xw[zo][yo][0] = __builtin_bit_cast(float, el);
            xw[zo][yo][1] = qf.x;
            xw[zo][yo][2] = qf.y;
            xw[zo][yo][3] = qf.z;
            xw[zo][yo][4] = qf.w;
            xw[zo][yo][5] = __builtin_bit_cast(float, er);
        }

        const float* Wc = weff + (size_t)(ch0 + cc) * 64;   // wave-uniform -> s_load
        #pragma unroll
        for (int zo = 0; zo < 3; zo++)
        #pragma unroll
        for (int pd = 0; pd < 2; pd++) {
            const int dd = zo - pd;
            if (dd < 0 || dd > 1) continue;
            const float* Wg = Wc + (pd * 2 + dd) * 16;
            #pragma unroll
            for (int ph = 0; ph < 2; ph++)
            #pragma unroll
            for (int pw = 0; pw < 2; pw++)
            #pragma unroll
            for (int dh = 0; dh < 2; dh++)
            #pragma unroll
            for (int dw = 0; dw < 2; dw++) {
                const float wgt = Wg[((ph * 2 + pw) * 2 + dh) * 2 + dw];
                #pragma unroll
                for (int j = 0; j < 4; j++)
                    acc[pd][ph][pw][j] += wgt * xw[zo][ph + dh][j + pw + dw];
            }
        }
    }

    // ---- in-block tree reduce over the 4 channel groups ----
    __syncthreads();
    if (wv == 1 || wv == 3) {
        float* R = red[wv >> 1];
        #pragma unroll
        for (int g = 0; g < 8; g++) {
            int pd = g >> 2, ph = (g >> 1) & 1, pw = g & 1;
            *(float4*)&R[L * 36 + g * 4] =
                make_float4(acc[pd][ph][pw][0], acc[pd][ph][pw][1],
                            acc[pd][ph][pw][2], acc[pd][ph][pw][3]);
        }
    }
    __syncthreads();
    if (wv == 0 || wv == 2) {
        const float* R = red[wv >> 1];
        #pragma unroll
        for (int g = 0; g < 8; g++) {
            int pd = g >> 2, ph = (g >> 1) & 1, pw = g & 1;
            float4 v = *(const float4*)&R[L * 36 + g * 4];
            acc[pd][ph][pw][0] += v.x; acc[pd][ph][pw][1] += v.y;
            acc[pd][ph][pw][2] += v.z; acc[pd][ph][pw][3] += v.w;
        }
    }
    __syncthreads();
    if (wv == 2) {
        float* R = red[0];
        #pragma unroll
        for (int g = 0; g < 8; g++) {
            int pd = g >> 2, ph = (g >> 1) & 1, pw = g & 1;
            *(float4*)&R[L * 36 + g * 4] =
                make_float4(acc[pd][ph][pw][0], acc[pd][ph][pw][1],
                            acc[pd][ph][pw][2], acc[pd][ph][pw][3]);
        }
    }
    __syncthreads();
    if (wv == 0) {
        const float bterm = bias[0] * 64.0f;
        float* on = out + (size_t)n * OSP;
        #pragma unroll
        for (int g = 0; g < 8; g++) {
            int pd = g >> 2, ph = (g >> 1) & 1, pw = g & 1;
            float4 v = *(const float4*)&red[0][L * 36 + g * 4];
            float t[4] = {acc[pd][ph][pw][0] + v.x, acc[pd][ph][pw][1] + v.y,
                          acc[pd][ph][pw][2] + v.z, acc[pd][ph][pw][3] + v.w};
            const int od = 2 * (Bd + md) + pd;
            const int oh = 2 * (Bh + mh) + ph;
            if (od < OUT_D && oh < OUT_D) {
                #pragma unroll
                for (int j = 0; j < 4; j++) {
                    int ow = 2 * (mwb + j) + pw;
                    if (ow < OUT_D)
                        on[(od * OUT_D + oh) * OUT_D + ow] = t[j] * 64.0f + bterm;
                }
            }
        }
    }
}

extern "C" void kernel_launch(void* const* d_in, const int* in_sizes, int n_in,
                              void* d_out, int out_size, void* d_ws, size_t ws_size,
                              hipStream_t stream) {
    const float* x      = (const float*)d_in[0];
    const float* weight = (const float*)d_in[1];
    const float* bias   = (const float*)d_in[2];
    float* out = (float*)d_out;
    float* weff = (float*)d_ws;        // 64*64 floats = 16 KB

    hipLaunchKernelGGL(weff_prep, dim3(64), dim3(64), 0, stream, weight, weff);

    dim3 grid(54 * BATCH, 1, 1);       // 864 blocks
    hipLaunchKernelGGL(tconv, grid, dim3(256), 0, stream, x, weff, bias, out);
}

// Round 7
// 151.469 us; speedup vs baseline: 1.9985x; 1.9985x over previous
//
#include <hip/hip_runtime.h>

// Problem constants
#define IN_C   64
#define OUT_D  47          // (24-1)*2 - 2*1 + 3
#define XD     24
#define XSP    (XD*XD*XD)  // 13824
#define OSP    (OUT_D*OUT_D*OUT_D) // 103823
#define BATCH  16

// Per-wave LDS: two channel-halves, each 60 rows (6z x 10y) x RS=12 floats.
// Row r holds x[gz=Bd-1+r/10][gy=Bh-1+r%10][gx=Bw-1..Bw+10] at idx 0..11.
// 12r mod 32 cycles {0,12,24,4,16,28,8,20}: 8 consecutive rows cover all 32
// banks once -> conflict-free b128 with th in the low 3 lane bits.
#define RS     12
#define NR     60
#define WBUF   (NR*RS)       // 720 floats per channel-half
#define WV_LDS (2*WBUF)      // 1440 floats per wave
#define LDS_TOT (4*WV_LDS)   // 5760 floats = 23 KB

typedef float f4u __attribute__((ext_vector_type(4), aligned(4)));

// Effective weights: weff[c*64 + (pd*2+dd)*16 + (((ph*2+pw)*2+dh)*2+dw)]
// Per dim: S(p=0,d=0)={2}, S(0,1)={0,1}, S(1,0)={1,2}, S(1,1)={0}
__global__ void weff_prep(const float* __restrict__ w, float* __restrict__ weff) {
    const int c = blockIdx.x;
    const int i = threadIdx.x;
    const int pd = i >> 5, dd = (i >> 4) & 1, ph = (i >> 3) & 1,
              pw = (i >> 2) & 1, dh = (i >> 1) & 1, dw = i & 1;
    const int st[2][2] = {{2, 0}, {1, 0}};   // start of S(p,d)
    const int ct[2][2] = {{1, 2}, {2, 1}};   // count of S(p,d)
    const int z0 = st[pd][dd], zc = ct[pd][dd];
    const int h0 = st[ph][dh], hc = ct[ph][dh];
    const int w0 = st[pw][dw], wn = ct[pw][dw];
    const float* wc = w + (size_t)c * 64 * 27;   // weight[c][0][*]
    float s = 0.f;
    for (int a = 0; a < zc; a++)
        for (int b = 0; b < hc; b++)
            for (int d = 0; d < wn; d++)
                s += wc[(z0 + a) * 9 + (h0 + b) * 3 + (w0 + d)];
    weff[c * 64 + i] = s;
}

// 864 blocks = 54 sp-tiles (m-tile 4x8x8) x 16 n (n in low 4 bits -> XCD
// locality: each XCD sees 2 n's = 7 MB slab). 256 threads = 4 waves; wave wv
// reduces channels [16wv,16wv+16) in a wave-PRIVATE double-half LDS buffer,
// two channels per iteration, barrier-free. Weights via readfirstlane ->
// provably uniform -> s_load -> SGPR operands in v_fmac_f32.
__global__ __launch_bounds__(256, 4) void tconv(const float* __restrict__ x,
                                                const float* __restrict__ weff,
                                                const float* __restrict__ bias,
                                                float* __restrict__ out) {
    __shared__ float xs[LDS_TOT];    // staging; overlaid by reduce scratch after
    const int b = blockIdx.x;
    const int n = b & 15;
    const int sp = b >> 4;           // 0..53
    const int tz = sp / 9;
    const int r9 = sp - tz * 9;
    const int ty = r9 / 3;
    const int tx = r9 - ty * 3;
    const int Bd = tz * 4, Bh = ty * 8, Bw = tx * 8;

    const int tid = threadIdx.x;
    const int wv = tid >> 6;
    const int L  = tid & 63;
    const int th = L & 7;
    const int tw = (L >> 3) & 1;
    const int td = L >> 4;           // 0..3

    float* H0 = xs + wv * WV_LDS;
    float* H1 = H0 + WBUF;

    // one-time zero fill (invalid halo rows must read as 0 forever)
    #pragma unroll
    for (int i = tid; i < LDS_TOT; i += 256) xs[i] = 0.f;
    __syncthreads();

    // ---- channel-invariant staging descriptors: 3 units/lane ----
    // unit e = u*60 + r (u = x-quad 0..2, r = row): 8-lane phases get
    // consecutive r -> perfect bank spread on the b128 writes.
    int gofs[3], lad[3], et[3];      // et: -1 skip, 0 full, 1 shift-left, 2 scalar
    #pragma unroll
    for (int k = 0; k < 3; k++) {
        int e = k * 64 + L;
        int u = e / 60;
        int r = e - u * 60;
        int z = r / 10;
        int y = r - z * 10;
        int gz = Bd - 1 + z, gy = Bh - 1 + y;
        bool rv = (e < 180) && ((unsigned)gz < (unsigned)XD) &&
                  ((unsigned)gy < (unsigned)XD);
        int gxs = Bw - 1 + 4 * u;
        int t;
        if (!rv) t = -1;
        else if (gxs < 0) t = 1;          // Bw=0,u=0: gx -1..2
        else if (gxs + 3 > XD - 1) t = 2; // Bw=16,u=2: gx 23..26
        else t = 0;
        et[k] = t;
        gofs[k] = (gz * XD + gy) * XD + (gxs < 0 ? 0 : gxs);
        lad[k] = r * RS + 4 * u;
    }

    const float* xg = x + ((size_t)n * IN_C + wv * 16) * XSP;

    // ---- prologue prefetch: channel pair 0 ----
    float4 preA[3], preB[3];
    #pragma unroll
    for (int k = 0; k < 3; k++) {
        if (et[k] < 0) { preA[k] = preB[k] = make_float4(0.f, 0.f, 0.f, 0.f); continue; }
        if (et[k] == 2) {
            preA[k] = make_float4(xg[gofs[k]], 0.f, 0.f, 0.f);
            preB[k] = make_float4(xg[XSP + gofs[k]], 0.f, 0.f, 0.f);
        } else {
            f4u qa = *(const f4u*)(xg + gofs[k]);
            f4u qb = *(const f4u*)(xg + XSP + gofs[k]);
            preA[k] = make_float4(qa.x, qa.y, qa.z, qa.w);
            preB[k] = make_float4(qb.x, qb.y, qb.z, qb.w);
        }
    }

    float acc[2][2][2][4] = {};      // [pd][ph][pw][j]

    // ---- barrier-free channel loop: 8 iterations x 2 channels ----
    #pragma unroll 1
    for (int it = 0; it < 8; it++) {
        // stage both channels from prefetch regs
        #pragma unroll
        for (int k = 0; k < 3; k++) {
            if (et[k] >= 0) {
                float4 ca = preA[k], cb = preB[k];
                if (et[k] == 1) {
                    ca = make_float4(0.f, ca.x, ca.y, ca.z);
                    cb = make_float4(0.f, cb.x, cb.y, cb.z);
                }
                *(float4*)&H0[lad[k]] = ca;
                *(float4*)&H1[lad[k]] = cb;
            }
        }
        // prefetch next pair (consumed next iteration)
        if (it + 1 < 8) {
            const float* xa = xg + (size_t)(2 * it + 2) * XSP;
            #pragma unroll
            for (int k = 0; k < 3; k++) {
                if (et[k] < 0) continue;
                if (et[k] == 2) {
                    preA[k] = make_float4(xa[gofs[k]], 0.f, 0.f, 0.f);
                    preB[k] = make_float4(xa[XSP + gofs[k]], 0.f, 0.f, 0.f);
                } else {
                    f4u qa = *(const f4u*)(xa + gofs[k]);
                    f4u qb = *(const f4u*)(xa + XSP + gofs[k]);
                    preA[k] = make_float4(qa.x, qa.y, qa.z, qa.w);
                    preB[k] = make_float4(qb.x, qb.y, qb.z, qb.w);
                }
            }
        }

        // provably wave-uniform weight base -> s_load / SGPR operands
        const int c0 = __builtin_amdgcn_readfirstlane(wv * 16 + 2 * it);
        #pragma unroll
        for (int half = 0; half < 2; half++) {
            const float* Hs = half ? H1 : H0;
            const float* Wc = weff + (size_t)(c0 + half) * 64;
            #pragma unroll
            for (int zo = 0; zo < 3; zo++) {
                float xv[3][6];
                #pragma unroll
                for (int dy = 0; dy < 3; dy++) {
                    int base = ((td + zo) * 10 + th + dy) * RS + 4 * tw;
                    float4 A = *(const float4*)&Hs[base];
                    float2 Bv = *(const float2*)&Hs[base + 4];
                    xv[dy][0] = A.x;  xv[dy][1] = A.y;  xv[dy][2] = A.z;
                    xv[dy][3] = A.w;  xv[dy][4] = Bv.x; xv[dy][5] = Bv.y;
                }
                #pragma unroll
                for (int pd = 0; pd < 2; pd++) {
                    const int dd = zo - pd;
                    if (dd < 0 || dd > 1) continue;
                    const float* Wg = Wc + (pd * 2 + dd) * 16;
                    #pragma unroll
                    for (int ph = 0; ph < 2; ph++)
                    #pragma unroll
                    for (int pw = 0; pw < 2; pw++)
                    #pragma unroll
                    for (int dh = 0; dh < 2; dh++)
                    #pragma unroll
                    for (int dw = 0; dw < 2; dw++) {
                        const float wgt = Wg[((ph * 2 + pw) * 2 + dh) * 2 + dw];
                        #pragma unroll
                        for (int j = 0; j < 4; j++)
                            acc[pd][ph][pw][j] += wgt * xv[ph + dh][j + pw + dw];
                    }
                }
            }
        }
    }

    // ---- in-block tree reduction over the 4 channel groups ----
    __syncthreads();
    float* R0 = xs;                  // 64*36 floats
    float* R1 = xs + 64 * 36;
    if (wv == 1 || wv == 3) {
        float* R = (wv == 1) ? R0 : R1;
        #pragma unroll
        for (int g = 0; g < 8; g++) {
            int pd = g >> 2, ph = (g >> 1) & 1, pw = g & 1;
            *(float4*)&R[L * 36 + g * 4] =
                make_float4(acc[pd][ph][pw][0], acc[pd][ph][pw][1],
                            acc[pd][ph][pw][2], acc[pd][ph][pw][3]);
        }
    }
    __syncthreads();
    if (wv == 0 || wv == 2) {
        const float* R = (wv == 0) ? R0 : R1;
        #pragma unroll
        for (int g = 0; g < 8; g++) {
            int pd = g >> 2, ph = (g >> 1) & 1, pw = g & 1;
            float4 v = *(const float4*)&R[L * 36 + g * 4];
            acc[pd][ph][pw][0] += v.x; acc[pd][ph][pw][1] += v.y;
            acc[pd][ph][pw][2] += v.z; acc[pd][ph][pw][3] += v.w;
        }
    }
    __syncthreads();
    if (wv == 2) {
        #pragma unroll
        for (int g = 0; g < 8; g++) {
            int pd = g >> 2, ph = (g >> 1) & 1, pw = g & 1;
            *(float4*)&R0[L * 36 + g * 4] =
                make_float4(acc[pd][ph][pw][0], acc[pd][ph][pw][1],
                            acc[pd][ph][pw][2], acc[pd][ph][pw][3]);
        }
    }
    __syncthreads();
    if (wv == 0) {
        const float bterm = bias[0] * 64.0f;
        float* on = out + (size_t)n * OSP;
        #pragma unroll
        for (int g = 0; g < 8; g++) {
            int pd = g >> 2, ph = (g >> 1) & 1, pw = g & 1;
            float4 v = *(const float4*)&R0[L * 36 + g * 4];
            float t[4] = {acc[pd][ph][pw][0] + v.x, acc[pd][ph][pw][1] + v.y,
                          acc[pd][ph][pw][2] + v.z, acc[pd][ph][pw][3] + v.w};
            const int od = 2 * (Bd + td) + pd;
            const int oh = 2 * (Bh + th) + ph;
            if (od < OUT_D && oh < OUT_D) {
                #pragma unroll
                for (int j = 0; j < 4; j++) {
                    int ow = 2 * (Bw + 4 * tw + j) + pw;
                    if (ow < OUT_D)
                        on[(od * OUT_D + oh) * OUT_D + ow] = t[j] * 64.0f + bterm;
                }
            }
        }
    }
}

extern "C" void kernel_launch(void* const* d_in, const int* in_sizes, int n_in,
                              void* d_out, int out_size, void* d_ws, size_t ws_size,
                              hipStream_t stream) {
    const float* x      = (const float*)d_in[0];
    const float* weight = (const float*)d_in[1];
    const float* bias   = (const float*)d_in[2];
    float* out = (float*)d_out;
    float* weff = (float*)d_ws;        // 64*64 floats = 16 KB

    hipLaunchKernelGGL(weff_prep, dim3(64), dim3(64), 0, stream, weight, weff);

    dim3 grid(54 * BATCH, 1, 1);       // 864 blocks, n in low 4 bits
    hipLaunchKernelGGL(tconv, grid, dim3(256), 0, stream, x, weff, bias, out);
}